// Round 1
// 984.232 us; speedup vs baseline: 1.0284x; 1.0284x over previous
//
#include <hip/hip_runtime.h>

typedef _Float16 half8 __attribute__((ext_vector_type(8)));
typedef _Float16 half4 __attribute__((ext_vector_type(4)));
typedef float floatx4 __attribute__((ext_vector_type(4)));

// ---------------- workspace layout (bytes) ----------------
// X fp16 region [0, 134217728) is dead after the projection GEMM; S/P alias it.
#define OFF_X    0L
#define OFF_S    0L                      // 4 batches * 2048*2048 fp32 = 67108864
#define OFF_P    67108864L               // 8 batches * 2048*2048 fp16 = 67108864
#define OFF_W    134217728L              // 1024*1024 fp16 = 2097152
#define OFF_QK   136314880L              // 65536*1024 fp16 (Q rows 0.., K rows 32768..)
#define OFF_KT   270532608L              // 16*1024*2048 fp16 = 67108864
#define OFF_MASK 337641472L              // 32768 u8
#define WS_NEED  337674240L

__device__ __forceinline__ void glds16(const void* g, void* l) {
  __builtin_amdgcn_global_load_lds(
      (__attribute__((address_space(1))) void*)(void*)(g),
      (__attribute__((address_space(3))) void*)(l), 16, 0, 0);
}

// ---------------- mask canonicalization ----------------
__global__ void mask_canon(const unsigned* __restrict__ raw,
                           unsigned char* __restrict__ outm) {
  __shared__ int flag;
  int t = threadIdx.x;
  if (t == 0) flag = 0;
  __syncthreads();
  int loc = 0;
  for (int i = t; i < 8192; i += 256)
    if (raw[i] > 1u) loc = 1;
  if (loc) flag = 1;
  __syncthreads();
  if (flag) {
    const unsigned char* b8 = (const unsigned char*)raw;
    for (int j = t; j < 32768; j += 256) outm[j] = (b8[j] != 0);
  } else {
    const int* r32 = (const int*)raw;
    for (int j = t; j < 32768; j += 256) outm[j] = (r32[j] != 0);
  }
}

// ---------------- fp32 -> fp16 convert ----------------
__global__ __launch_bounds__(256) void cvt_f32_f16(const float* __restrict__ x,
                                                   _Float16* __restrict__ y, long n) {
  long i = ((long)blockIdx.x * 256 + threadIdx.x) * 4;
  if (i + 3 < n) {
    float4 v = *(const float4*)(x + i);
    half4 h;
    h[0] = (_Float16)v.x; h[1] = (_Float16)v.y;
    h[2] = (_Float16)v.z; h[3] = (_Float16)v.w;
    *(half4*)(y + i) = h;
  }
}

// ---------------- NT GEMM, 256x256 tile, 8-wave, 8-phase counted-vmcnt ----------------
// C[m,n] = sum_k A[m,k]*B[n,k]; A/B row stride == K.
// 512 threads = 8 waves (2M x 4N), per-wave output 128x64, BK=64, 16x16x32 f16 MFMA.
// LDS 128 KiB: double-buffered A/B K-tiles; rows 128B = 8 chunks of 16B,
// chunk XOR-swizzled by (row&7) (conflict-free, measured 0 on the 128^2 version).
// Schedule per K-tile t (buf p = t&1):
//   top: vmcnt(4)  -- outstanding = {A(t):4, B(t+1):4}; keep newest 4 => tile t drained
//   ph1: read B all(8)+A mi0-1(4); stage A(t+1) r0,r1 -> buf p^1; bar; lgkm0; 16 MFMA; bar
//   ph2: read A mi2-3;            stage A(t+1) r2,r3;             ...
//   ph3: read A mi4-5;            stage B(t+2) r0,r1 -> buf p (B region free after ph1)
//   ph4: read A mi6-7;            stage B(t+2) r2,r3
// Loads never drain to 0 inside the loop.
template <bool EPI>
__global__ __launch_bounds__(512, 2)
void gemm_nt8(const _Float16* __restrict__ A, long sAz,
              const _Float16* __restrict__ B, long sBz,
              void* __restrict__ Cv, long sCz,
              const float* __restrict__ bias, int K, int ldc) {
  __shared__ _Float16 As[2][256 * 64];
  __shared__ _Float16 Bs[2][256 * 64];
  const int t = threadIdx.x;
  const int l = t & 63;
  const int w = t >> 6;
  const int wr = w >> 2, wc = w & 3;
  A += (long)blockIdx.z * sAz + (long)blockIdx.y * 256 * (long)K;
  B += (long)blockIdx.z * sBz + (long)blockIdx.x * 256 * (long)K;
  const int l15 = l & 15, quad = l >> 4;
  const int srow = l >> 3;
  const int gchunk = (l & 7) ^ (srow & 7);
  const int sbase = w * 8;                       // wave's 8-row slice in a 64-row round
  const int cc0 = quad ^ (l15 & 7);
  const int aoff0 = (wr * 128 + l15) * 64 + cc0 * 8;
  const int aoff1 = (wr * 128 + l15) * 64 + (cc0 ^ 4) * 8;
  const int boff0 = (wc * 64 + l15) * 64 + cc0 * 8;
  const int boff1 = (wc * 64 + l15) * 64 + (cc0 ^ 4) * 8;

  floatx4 acc[8][4] = {};
  const int NT = K >> 6;

#define STG(src, dst, rnd, kt)                                                   \
  glds16((src) + (long)((rnd) * 64 + sbase + srow) * K + (kt) + gchunk * 8,      \
         (dst) + ((rnd) * 64 + sbase) * 64)

  // prologue: A(0) x4, B(0) x4, B(1) x4  (A(1) staged inside iteration 0)
  STG(A, As[0], 0, 0); STG(A, As[0], 1, 0); STG(A, As[0], 2, 0); STG(A, As[0], 3, 0);
  STG(B, Bs[0], 0, 0); STG(B, Bs[0], 1, 0); STG(B, Bs[0], 2, 0); STG(B, Bs[0], 3, 0);
  {
    const int k1 = (NT > 1) ? 64 : 0;
    STG(B, Bs[1], 0, k1); STG(B, Bs[1], 1, k1); STG(B, Bs[1], 2, k1); STG(B, Bs[1], 3, k1);
  }

#define READ_A(afv, m0)                                           \
  afv[0][0] = *(const half8*)(Ap + aoff0 + (m0) * 1024);          \
  afv[0][1] = *(const half8*)(Ap + aoff1 + (m0) * 1024);          \
  afv[1][0] = *(const half8*)(Ap + aoff0 + ((m0) + 1) * 1024);    \
  afv[1][1] = *(const half8*)(Ap + aoff1 + ((m0) + 1) * 1024);

#define PHASE_TAIL(m0, afv)                                                                                \
  __builtin_amdgcn_s_barrier();                                                                            \
  asm volatile("s_waitcnt lgkmcnt(0)" ::: "memory");                                                       \
  __builtin_amdgcn_s_setprio(1);                                                                           \
  _Pragma("unroll")                                                                                        \
  for (int ni = 0; ni < 4; ++ni) {                                                                         \
    acc[m0][ni] = __builtin_amdgcn_mfma_f32_16x16x32_f16(afv[0][0], bf[ni][0], acc[m0][ni], 0, 0, 0);      \
    acc[m0][ni] = __builtin_amdgcn_mfma_f32_16x16x32_f16(afv[0][1], bf[ni][1], acc[m0][ni], 0, 0, 0);      \
    acc[(m0) + 1][ni] =                                                                                    \
        __builtin_amdgcn_mfma_f32_16x16x32_f16(afv[1][0], bf[ni][0], acc[(m0) + 1][ni], 0, 0, 0);          \
    acc[(m0) + 1][ni] =                                                                                    \
        __builtin_amdgcn_mfma_f32_16x16x32_f16(afv[1][1], bf[ni][1], acc[(m0) + 1][ni], 0, 0, 0);          \
  }                                                                                                        \
  __builtin_amdgcn_s_setprio(0);                                                                           \
  __builtin_amdgcn_s_barrier();

  for (int tt = 0; tt < NT; ++tt) {
    const _Float16* Ap = As[tt & 1];
    const _Float16* Bp = Bs[tt & 1];
    _Float16* Anx = As[(tt + 1) & 1];
    _Float16* Bnx = Bs[tt & 1];
    const int kt1 = ((tt + 1 < NT) ? tt + 1 : NT - 1) * 64;   // clamped junk at tail: safe, never read
    const int kt2 = ((tt + 2 < NT) ? tt + 2 : NT - 1) * 64;

    asm volatile("s_waitcnt vmcnt(4)" ::: "memory");
    __builtin_amdgcn_s_barrier();
    asm volatile("" ::: "memory");   // pin LDS reads after the barrier (cross-wave staging publish)

    half8 bf[4][2], af0[2][2], af1[2][2];
    // ---- phase 1 ----
#pragma unroll
    for (int ni = 0; ni < 4; ++ni) {
      bf[ni][0] = *(const half8*)(Bp + boff0 + ni * 1024);
      bf[ni][1] = *(const half8*)(Bp + boff1 + ni * 1024);
    }
    READ_A(af0, 0)
    STG(A, Anx, 0, kt1);
    STG(A, Anx, 1, kt1);
    PHASE_TAIL(0, af0)
    // ---- phase 2 ----
    READ_A(af1, 2)
    STG(A, Anx, 2, kt1);
    STG(A, Anx, 3, kt1);
    PHASE_TAIL(2, af1)
    // ---- phase 3 ----
    READ_A(af0, 4)
    STG(B, Bnx, 0, kt2);
    STG(B, Bnx, 1, kt2);
    PHASE_TAIL(4, af0)
    // ---- phase 4 ----
    READ_A(af1, 6)
    STG(B, Bnx, 2, kt2);
    STG(B, Bnx, 3, kt2);
    PHASE_TAIL(6, af1)
  }
  // drain stray tail prefetches before LDS deallocation at endpgm
  asm volatile("s_waitcnt vmcnt(0)" ::: "memory");
#undef STG
#undef READ_A
#undef PHASE_TAIL

  const int rowb = quad * 4;
  const long cbase = (long)blockIdx.z * sCz + (long)blockIdx.y * 256 * (long)ldc + blockIdx.x * 256;
  if constexpr (EPI) {
    _Float16* Cp = (_Float16*)Cv + cbase;
    float bv[4];
#pragma unroll
    for (int ni = 0; ni < 4; ++ni) bv[ni] = bias[blockIdx.x * 256 + wc * 64 + ni * 16 + l15];
#pragma unroll
    for (int mi = 0; mi < 8; ++mi)
#pragma unroll
      for (int ni = 0; ni < 4; ++ni) {
        const int col = wc * 64 + ni * 16 + l15;
#pragma unroll
        for (int p = 0; p < 4; ++p) {
          const int row = wr * 128 + mi * 16 + rowb + p;
          Cp[(long)row * ldc + col] = (_Float16)fmaxf(acc[mi][ni][p] + bv[ni], 0.f);
        }
      }
  } else {
    float* Cp = (float*)Cv + cbase;
#pragma unroll
    for (int mi = 0; mi < 8; ++mi)
#pragma unroll
      for (int ni = 0; ni < 4; ++ni) {
        const int col = wc * 64 + ni * 16 + l15;
#pragma unroll
        for (int p = 0; p < 4; ++p) {
          const int row = wr * 128 + mi * 16 + rowb + p;
          Cp[(long)row * ldc + col] = acc[mi][ni][p];
        }
      }
  }
}

// ---------------- K transpose (per batch, fp16) ----------------
__global__ __launch_bounds__(256) void transpose_k(const _Float16* __restrict__ Km,
                                                   _Float16* __restrict__ KT) {
  __shared__ _Float16 tile[64 * 72];
  const int t = threadIdx.x;
  const long b = blockIdx.z;
  const _Float16* src = Km + (b * 2048 + blockIdx.x * 64) * 1024 + blockIdx.y * 64;
  {
    const int jl = t >> 2, hc = (t & 3) * 16;
    half8 v0 = *(const half8*)(src + (long)jl * 1024 + hc);
    half8 v1 = *(const half8*)(src + (long)jl * 1024 + hc + 8);
    *(half8*)&tile[jl * 72 + hc] = v0;
    *(half8*)&tile[jl * 72 + hc + 8] = v1;
  }
  __syncthreads();
  {
    const int hl = t >> 2, jc = (t & 3) * 16;
    half8 o0, o1;
#pragma unroll
    for (int jj = 0; jj < 8; jj++) o0[jj] = tile[(jc + jj) * 72 + hl];
#pragma unroll
    for (int jj = 0; jj < 8; jj++) o1[jj] = tile[(jc + 8 + jj) * 72 + hl];
    long off = (b * 1024 + blockIdx.y * 64 + hl) * 2048 + blockIdx.x * 64 + jc;
    *(half8*)(KT + off) = o0;
    *(half8*)(KT + off + 8) = o1;
  }
}

// ---------------- masked softmax: S fp32 row -> P fp16 row ----------------
__global__ __launch_bounds__(256) void softmax_k(const float* __restrict__ S,
                                                 _Float16* __restrict__ P,
                                                 const unsigned char* __restrict__ mask,
                                                 int b0) {
  const int i = blockIdx.x, z = blockIdx.y, t = threadIdx.x;
  const float* s = S + ((long)z * 2048 + i) * 2048;
  const unsigned char* mrow = mask + (long)(b0 + z) * 2048;
  const int base0 = t * 4, base1 = 1024 + t * 4;
  float4 a0 = *(const float4*)(s + base0);
  float4 a1 = *(const float4*)(s + base1);
  float v[8] = {a0.x, a0.y, a0.z, a0.w, a1.x, a1.y, a1.z, a1.w};
  const float NINF = -__builtin_inff();
#pragma unroll
  for (int k = 0; k < 4; k++) {
    if (mrow[base0 + k]) v[k] = NINF;
    if (mrow[base1 + k]) v[4 + k] = NINF;
  }
  float mx = v[0];
#pragma unroll
  for (int k = 1; k < 8; k++) mx = fmaxf(mx, v[k]);
#pragma unroll
  for (int o = 32; o >= 1; o >>= 1) mx = fmaxf(mx, __shfl_xor(mx, o, 64));
  __shared__ float redm[4], reds[4];
  if ((t & 63) == 0) redm[t >> 6] = mx;
  __syncthreads();
  mx = fmaxf(fmaxf(redm[0], redm[1]), fmaxf(redm[2], redm[3]));
  float e[8], sm = 0.f;
#pragma unroll
  for (int k = 0; k < 8; k++) { e[k] = __expf(v[k] - mx); sm += e[k]; }
#pragma unroll
  for (int o = 32; o >= 1; o >>= 1) sm += __shfl_xor(sm, o, 64);
  if ((t & 63) == 0) reds[t >> 6] = sm;
  __syncthreads();
  sm = reds[0] + reds[1] + reds[2] + reds[3];
  const float inv = 1.0f / sm;   // never a fully-masked row
  _Float16* p = P + ((long)z * 2048 + i) * 2048;
  half4 h0, h1;
#pragma unroll
  for (int k = 0; k < 4; k++) { h0[k] = (_Float16)(e[k] * inv); h1[k] = (_Float16)(e[4 + k] * inv); }
  *(half4*)(p + base0) = h0;
  *(half4*)(p + base1) = h1;
}

extern "C" void kernel_launch(void* const* d_in, const int* in_sizes, int n_in,
                              void* d_out, int out_size, void* d_ws, size_t ws_size,
                              hipStream_t stream) {
  (void)in_sizes; (void)n_in; (void)out_size;
  if ((long)ws_size < WS_NEED) return;  // workspace too small: leave out poisoned as a clear signal

  const float* inp  = (const float*)d_in[0];
  const float* ctx  = (const float*)d_in[1];
  const unsigned* msk = (const unsigned*)d_in[2];
  const float* W    = (const float*)d_in[3];
  const float* bias = (const float*)d_in[4];
  float* out = (float*)d_out;
  char* ws = (char*)d_ws;

  _Float16* Xf   = (_Float16*)(ws + OFF_X);
  float*    Sb   = (float*)(ws + OFF_S);
  _Float16* Pb   = (_Float16*)(ws + OFF_P);
  _Float16* Wf   = (_Float16*)(ws + OFF_W);
  _Float16* QK   = (_Float16*)(ws + OFF_QK);
  _Float16* KT   = (_Float16*)(ws + OFF_KT);
  unsigned char* Mc = (unsigned char*)(ws + OFF_MASK);

  // 1. canonical mask
  mask_canon<<<1, 256, 0, stream>>>(msk, Mc);
  // 2. fp32 -> fp16 (inp | ctx | W)
  cvt_f32_f16<<<32768, 256, 0, stream>>>(inp, Xf, 33554432L);
  cvt_f32_f16<<<32768, 256, 0, stream>>>(ctx, Xf + 33554432L, 33554432L);
  cvt_f32_f16<<<1024, 256, 0, stream>>>(W, Wf, 1048576L);
  // 3. projection: QK = relu([inp;ctx] @ W^T + b), M=65536, N=1024, K=1024
  gemm_nt8<true><<<dim3(4, 256, 1), 512, 0, stream>>>(Xf, 0L, Wf, 0L, (void*)QK, 0L,
                                                      bias, 1024, 1024);
  // 4. K^T per batch
  transpose_k<<<dim3(32, 16, 16), 256, 0, stream>>>(QK + 32768L * 1024, KT);
  // 5. two groups of 8 batches: (scores -> softmax) per 4-batch quad, then one PV for 8
  for (int g = 0; g < 2; g++) {
    for (int q = 0; q < 2; q++) {
      const int bp = g * 2 + q;
      const _Float16* Aq = QK + (long)bp * 4 * 2048 * 1024;
      const _Float16* Bk = QK + (32768L + (long)bp * 4 * 2048) * 1024;
      gemm_nt8<false><<<dim3(8, 8, 4), 512, 0, stream>>>(Aq, 2048L * 1024, Bk, 2048L * 1024,
                                                         (void*)Sb, 2048L * 2048, nullptr,
                                                         1024, 2048);
      softmax_k<<<dim3(2048, 4), 256, 0, stream>>>(Sb, Pb + (long)q * 4 * 2048 * 2048, Mc, bp * 4);
    }
    gemm_nt8<false><<<dim3(4, 8, 8), 512, 0, stream>>>(Pb, 2048L * 2048,
                                                       KT + (long)g * 8 * 1024 * 2048,
                                                       1024L * 2048,
                                                       (void*)(out + (long)g * 8 * 2048 * 1024),
                                                       2048L * 1024, nullptr, 2048, 1024);
  }
}

// Round 2
// 875.580 us; speedup vs baseline: 1.1560x; 1.1241x over previous
//
#include <hip/hip_runtime.h>

typedef _Float16 half8 __attribute__((ext_vector_type(8)));
typedef _Float16 half4 __attribute__((ext_vector_type(4)));
typedef float floatx4 __attribute__((ext_vector_type(4)));

// ---------------- workspace layout (bytes) ----------------
#define OFF_S    0L                      // 4 batches * 2048*2048 fp32 = 67108864
#define OFF_P    67108864L               // 8 batches * 2048*2048 fp16 = 67108864
#define OFF_W    134217728L              // 1024*1024 fp16 = 2097152
#define OFF_QK   136314880L              // 65536*1024 fp16 (Q rows 0.., K rows 32768..)
#define OFF_KT   270532608L              // 16*1024*2048 fp16 = 67108864
#define OFF_MASK 337641472L              // 32768 u8
#define WS_NEED  337674240L

__device__ __forceinline__ void glds16(const void* g, void* l) {
  __builtin_amdgcn_global_load_lds(
      (__attribute__((address_space(1))) void*)(void*)(g),
      (__attribute__((address_space(3))) void*)(l), 16, 0, 0);
}

// ---------------- mask canonicalization ----------------
__global__ void mask_canon(const unsigned* __restrict__ raw,
                           unsigned char* __restrict__ outm) {
  __shared__ int flag;
  int t = threadIdx.x;
  if (t == 0) flag = 0;
  __syncthreads();
  int loc = 0;
  for (int i = t; i < 8192; i += 256)
    if (raw[i] > 1u) loc = 1;
  if (loc) flag = 1;
  __syncthreads();
  if (flag) {
    const unsigned char* b8 = (const unsigned char*)raw;
    for (int j = t; j < 32768; j += 256) outm[j] = (b8[j] != 0);
  } else {
    const int* r32 = (const int*)raw;
    for (int j = t; j < 32768; j += 256) outm[j] = (r32[j] != 0);
  }
}

// ---------------- fp32 -> fp16 convert (W only now) ----------------
__global__ __launch_bounds__(256) void cvt_f32_f16(const float* __restrict__ x,
                                                   _Float16* __restrict__ y, long n) {
  long i = ((long)blockIdx.x * 256 + threadIdx.x) * 4;
  if (i + 3 < n) {
    float4 v = *(const float4*)(x + i);
    half4 h;
    h[0] = (_Float16)v.x; h[1] = (_Float16)v.y;
    h[2] = (_Float16)v.z; h[3] = (_Float16)v.w;
    *(half4*)(y + i) = h;
  }
}

// ---------------- NT GEMM, 256x256 tile, 8-wave, slim-barrier 4-phase ----------------
// C[m,n] = sum_k A[m,k]*B[n,k]; A/B row stride == K.
// 512 threads = 8 waves (2M x 4N), per-wave 128x64, BK=64, 16x16x32 f16 MFMA.
// Phases = (mi-half, k32); bf[] reused across the two mi-half phases of one k32
// Phase = [ds_reads; stage-issue; lgkmcnt(0); s_barrier; 16 MFMA]  (reads complete
// BEFORE the barrier -> any wave past the barrier implies ALL reads of that phase
// are done; later-phase staging into the just-read regions is then race-free).
// F32A: A staged from fp32 global via regs (issue ph1, cvt+ds_write ph4, ~3-phase
// latency cover); fp32->fp16 conversion fused, no separate cvt pass.
// B prefetch: glds16 2 tiles ahead, issued only in ph4 (B(t) ph3-reads complete
// before ph4's barrier-publish of the issue point).
// vmcnt discipline: fp16 path drains A(t+1) with vmcnt(4) at iter end (keeps
// B(t+2) in flight); F32A path needs no explicit loop vmcnt (cvt's dataflow wait
// drains the older B glds in-order).
template <bool EPI, bool F32A>
__global__ __launch_bounds__(512, 2)
void gemm_nt8(const _Float16* __restrict__ A, const float* __restrict__ A0,
              const float* __restrict__ A1, long sAz,
              const _Float16* __restrict__ B, long sBz,
              void* __restrict__ Cv, long sCz,
              const float* __restrict__ bias, int K, int ldc) {
  __shared__ _Float16 lds[256 * 264];   // 135168 B; GEMM uses first 131072 (As/Bs)
  const int t = threadIdx.x;
  const int l = t & 63;
  const int w = t >> 6;
  const int wr = w >> 2, wc = w & 3;
  const int l15 = l & 15, quad = l >> 4;
  const int srow = l >> 3;
  const int gchunk = (l & 7) ^ (srow & 7);
  const int sbase = w * 8;

  const _Float16* Ag = nullptr;
  const float* Af = nullptr;
  if constexpr (F32A) {
    const int hgy = (int)gridDim.y >> 1;
    Af = ((int)blockIdx.y < hgy) ? A0 + (long)blockIdx.y * 256 * (long)K
                                 : A1 + (long)((int)blockIdx.y - hgy) * 256 * (long)K;
  } else {
    Ag = A + (long)blockIdx.z * sAz + (long)blockIdx.y * 256 * (long)K;
  }
  const _Float16* Bg = B + (long)blockIdx.z * sBz + (long)blockIdx.x * 256 * (long)K;

  _Float16* As0 = lds;            // [2][16384] halves
  _Float16* Bs0 = lds + 32768;    // [2][16384] halves

  // fragment LDS offsets (halves); chunk XOR-swizzle by row&7 (== l15&7 here)
  auto aoff = [&](int mi) {
    const int row = wr * 128 + mi * 16 + l15;
    return row * 64 + ((quad ^ (row & 7)) << 3);
  };
  auto boff = [&](int ni) {
    const int row = wc * 64 + ni * 16 + l15;
    return row * 64 + ((quad ^ (row & 7)) << 3);
  };

  // F32A staging geometry
  const int frow = t >> 4;             // 0..31 (8 passes of 32 rows)
  const int fcol = (t & 15) * 4;       // float column
  const int fwch = (t & 15) >> 1;      // 16B chunk in 128B row
  const int fsub = (t & 1) * 4;        // half offset within chunk

  floatx4 acc[8][4] = {};
  float4 fA[8];
  const int NT = K >> 6;

#define STGA(dst, rnd, kt)                                                        \
  glds16(Ag + (long)((rnd) * 64 + sbase + srow) * K + (kt) + gchunk * 8,          \
         (dst) + ((rnd) * 64 + sbase) * 64)
#define STGB(dst, rnd, kt)                                                        \
  glds16(Bg + (long)((rnd) * 64 + sbase + srow) * K + (kt) + gchunk * 8,          \
         (dst) + ((rnd) * 64 + sbase) * 64)
#define PH_SYNC()                                                                 \
  do {                                                                            \
    asm volatile("s_waitcnt lgkmcnt(0)" ::: "memory");                            \
    __builtin_amdgcn_s_barrier();                                                 \
    __builtin_amdgcn_sched_barrier(8); /* only MFMA may cross */                  \
  } while (0)
#define MM(mh)                                                                    \
  do {                                                                            \
    __builtin_amdgcn_s_setprio(1);                                                \
    _Pragma("unroll") for (int i_ = 0; i_ < 4; ++i_)                              \
        _Pragma("unroll") for (int n_ = 0; n_ < 4; ++n_)                          \
            acc[(mh) * 4 + i_][n_] = __builtin_amdgcn_mfma_f32_16x16x32_f16(      \
                af[i_], bf[n_], acc[(mh) * 4 + i_][n_], 0, 0, 0);                 \
    __builtin_amdgcn_s_setprio(0);                                                \
  } while (0)

  // ---------------- prologue ----------------
  if constexpr (F32A) {
#pragma unroll
    for (int p = 0; p < 8; ++p)
      fA[p] = *(const float4*)(Af + (long)(frow + 32 * p) * K + fcol);
#pragma unroll
    for (int r = 0; r < 4; ++r) STGB(Bs0, r, 0);
    {
      const int k1 = (NT > 1 ? 64 : 0);
#pragma unroll
      for (int r = 0; r < 4; ++r) STGB(Bs0 + 16384, r, k1);
    }
#pragma unroll
    for (int p = 0; p < 8; ++p) {
      half4 h;
      h[0] = (_Float16)fA[p].x; h[1] = (_Float16)fA[p].y;
      h[2] = (_Float16)fA[p].z; h[3] = (_Float16)fA[p].w;
      const int row = frow + 32 * p;
      *(half4*)(As0 + row * 64 + ((fwch ^ (row & 7)) << 3) + fsub) = h;
    }
    asm volatile("s_waitcnt vmcnt(4) lgkmcnt(0)" ::: "memory");  // drain B(0); keep B(1)
    __builtin_amdgcn_s_barrier();
  } else {
#pragma unroll
    for (int r = 0; r < 4; ++r) STGA(As0, r, 0);
#pragma unroll
    for (int r = 0; r < 4; ++r) STGB(Bs0, r, 0);
    {
      const int k1 = (NT > 1 ? 64 : 0);
#pragma unroll
      for (int r = 0; r < 4; ++r) STGB(Bs0 + 16384, r, k1);
    }
    asm volatile("s_waitcnt vmcnt(4)" ::: "memory");  // drain A(0)+B(0); keep B(1)
    __builtin_amdgcn_s_barrier();
  }

  // ---------------- main loop ----------------
  for (int tt = 0; tt < NT; ++tt) {
    const _Float16* Ap = As0 + (tt & 1) * 16384;
    const _Float16* Bp = Bs0 + (tt & 1) * 16384;
    _Float16* Anx = As0 + ((tt + 1) & 1) * 16384;
    _Float16* Bnx = Bs0 + (tt & 1) * 16384;  // B(t+2) parity == t
    const int kt1 = ((tt + 1 < NT) ? tt + 1 : NT - 1) << 6;  // clamped junk: never read
    const int kt2 = ((tt + 2 < NT) ? tt + 2 : NT - 1) << 6;
    half8 af[4], bf[4];

    // ---- ph1: bf(k0) + af(mh0,k0); issue A(t+1) ----
#pragma unroll
    for (int ni = 0; ni < 4; ++ni) bf[ni] = *(const half8*)(Bp + boff(ni));
#pragma unroll
    for (int i = 0; i < 4; ++i) af[i] = *(const half8*)(Ap + aoff(i));
    if constexpr (F32A) {
#pragma unroll
      for (int p = 0; p < 8; ++p)
        fA[p] = *(const float4*)(Af + (long)(frow + 32 * p) * K + kt1 + fcol);
    } else {
      STGA(Anx, 0, kt1);
      STGA(Anx, 1, kt1);
    }
    PH_SYNC();
    MM(0);

    // ---- ph2: af(mh1,k0) ----
#pragma unroll
    for (int i = 0; i < 4; ++i) af[i] = *(const half8*)(Ap + aoff(4 + i));
    if constexpr (!F32A) {
      STGA(Anx, 2, kt1);
      STGA(Anx, 3, kt1);
    }
    PH_SYNC();
    MM(1);

    // ---- ph3: bf(k1) + af(mh0,k1) ----
#pragma unroll
    for (int ni = 0; ni < 4; ++ni) bf[ni] = *(const half8*)(Bp + (boff(ni) ^ 32));
#pragma unroll
    for (int i = 0; i < 4; ++i) af[i] = *(const half8*)(Ap + (aoff(i) ^ 32));
    PH_SYNC();
    MM(0);

    // ---- ph4: af(mh1,k1); write A(t+1) (F32A); issue B(t+2) ----
#pragma unroll
    for (int i = 0; i < 4; ++i) af[i] = *(const half8*)(Ap + (aoff(4 + i) ^ 32));
    if constexpr (F32A) {
#pragma unroll
      for (int p = 0; p < 8; ++p) {  // dataflow wait drains older B(t+1) glds too
        half4 h;
        h[0] = (_Float16)fA[p].x; h[1] = (_Float16)fA[p].y;
        h[2] = (_Float16)fA[p].z; h[3] = (_Float16)fA[p].w;
        const int row = frow + 32 * p;
        *(half4*)(Anx + row * 64 + ((fwch ^ (row & 7)) << 3) + fsub) = h;
      }
#pragma unroll
      for (int r = 0; r < 4; ++r) STGB(Bnx, r, kt2);
      PH_SYNC();
      MM(1);
    } else {
#pragma unroll
      for (int r = 0; r < 4; ++r) STGB(Bnx, r, kt2);
      PH_SYNC();
      MM(1);
      asm volatile("s_waitcnt vmcnt(4)" ::: "memory");  // drain A(t+1); keep B(t+2)
      __builtin_amdgcn_s_barrier();
    }
  }
  asm volatile("s_waitcnt vmcnt(0)" ::: "memory");  // tail junk glds before LDS reuse
  __syncthreads();
#undef STGA
#undef STGB
#undef PH_SYNC
#undef MM

  // ---------------- epilogue ----------------
  const long cbase = (long)blockIdx.z * sCz + (long)blockIdx.y * 256 * (long)ldc +
                     (long)blockIdx.x * 256;
  const int rowb = quad * 4;
  if constexpr (EPI) {
    // relu+bias, bounce through swizzled LDS tile (stride 264, chunk^row&7), then
    // fully-coalesced half8 stores.
    float bv[4];
#pragma unroll
    for (int ni = 0; ni < 4; ++ni) bv[ni] = bias[blockIdx.x * 256 + wc * 64 + ni * 16 + l15];
#pragma unroll
    for (int mi = 0; mi < 8; ++mi)
#pragma unroll
      for (int ni = 0; ni < 4; ++ni) {
        const int col = wc * 64 + ni * 16 + l15;
#pragma unroll
        for (int p = 0; p < 4; ++p) {
          const int row = wr * 128 + mi * 16 + rowb + p;
          lds[row * 264 + (((col >> 3) ^ (row & 7)) << 3) + (col & 7)] =
              (_Float16)fmaxf(acc[mi][ni][p] + bv[ni], 0.f);
        }
      }
    __syncthreads();
    _Float16* Cp = (_Float16*)Cv + cbase;
#pragma unroll
    for (int pp = 0; pp < 16; ++pp) {
      const int r = (t >> 5) + 16 * pp;
      const int c = t & 31;
      half8 v = *(const half8*)(lds + r * 264 + ((c ^ (r & 7)) << 3));
      *(half8*)(Cp + (long)r * ldc + c * 8) = v;
    }
  } else {
    float* Cp = (float*)Cv + cbase;
#pragma unroll
    for (int mi = 0; mi < 8; ++mi)
#pragma unroll
      for (int ni = 0; ni < 4; ++ni) {
        const int col = wc * 64 + ni * 16 + l15;
#pragma unroll
        for (int p = 0; p < 4; ++p) {
          const int row = wr * 128 + mi * 16 + rowb + p;
          Cp[(long)row * ldc + col] = acc[mi][ni][p];
        }
      }
  }
}

// ---------------- K transpose (per batch, fp16) ----------------
__global__ __launch_bounds__(256) void transpose_k(const _Float16* __restrict__ Km,
                                                   _Float16* __restrict__ KT) {
  __shared__ _Float16 tile[64 * 72];
  const int t = threadIdx.x;
  const long b = blockIdx.z;
  const _Float16* src = Km + (b * 2048 + blockIdx.x * 64) * 1024 + blockIdx.y * 64;
  {
    const int jl = t >> 2, hc = (t & 3) * 16;
    half8 v0 = *(const half8*)(src + (long)jl * 1024 + hc);
    half8 v1 = *(const half8*)(src + (long)jl * 1024 + hc + 8);
    *(half8*)&tile[jl * 72 + hc] = v0;
    *(half8*)&tile[jl * 72 + hc + 8] = v1;
  }
  __syncthreads();
  {
    const int hl = t >> 2, jc = (t & 3) * 16;
    half8 o0, o1;
#pragma unroll
    for (int jj = 0; jj < 8; jj++) o0[jj] = tile[(jc + jj) * 72 + hl];
#pragma unroll
    for (int jj = 0; jj < 8; jj++) o1[jj] = tile[(jc + 8 + jj) * 72 + hl];
    long off = (b * 1024 + blockIdx.y * 64 + hl) * 2048 + blockIdx.x * 64 + jc;
    *(half8*)(KT + off) = o0;
    *(half8*)(KT + off + 8) = o1;
  }
}

// ---------------- masked softmax: S fp32 row -> P fp16 row ----------------
__global__ __launch_bounds__(256) void softmax_k(const float* __restrict__ S,
                                                 _Float16* __restrict__ P,
                                                 const unsigned char* __restrict__ mask,
                                                 int b0) {
  const int i = blockIdx.x, z = blockIdx.y, t = threadIdx.x;
  const float* s = S + ((long)z * 2048 + i) * 2048;
  const unsigned char* mrow = mask + (long)(b0 + z) * 2048;
  const int base0 = t * 4, base1 = 1024 + t * 4;
  float4 a0 = *(const float4*)(s + base0);
  float4 a1 = *(const float4*)(s + base1);
  float v[8] = {a0.x, a0.y, a0.z, a0.w, a1.x, a1.y, a1.z, a1.w};
  const float NINF = -__builtin_inff();
#pragma unroll
  for (int k = 0; k < 4; k++) {
    if (mrow[base0 + k]) v[k] = NINF;
    if (mrow[base1 + k]) v[4 + k] = NINF;
  }
  float mx = v[0];
#pragma unroll
  for (int k = 1; k < 8; k++) mx = fmaxf(mx, v[k]);
#pragma unroll
  for (int o = 32; o >= 1; o >>= 1) mx = fmaxf(mx, __shfl_xor(mx, o, 64));
  __shared__ float redm[4], reds[4];
  if ((t & 63) == 0) redm[t >> 6] = mx;
  __syncthreads();
  mx = fmaxf(fmaxf(redm[0], redm[1]), fmaxf(redm[2], redm[3]));
  float e[8], sm = 0.f;
#pragma unroll
  for (int k = 0; k < 8; k++) { e[k] = __expf(v[k] - mx); sm += e[k]; }
#pragma unroll
  for (int o = 32; o >= 1; o >>= 1) sm += __shfl_xor(sm, o, 64);
  if ((t & 63) == 0) reds[t >> 6] = sm;
  __syncthreads();
  sm = reds[0] + reds[1] + reds[2] + reds[3];
  const float inv = 1.0f / sm;   // never a fully-masked row
  _Float16* p = P + ((long)z * 2048 + i) * 2048;
  half4 h0, h1;
#pragma unroll
  for (int k = 0; k < 4; k++) { h0[k] = (_Float16)(e[k] * inv); h1[k] = (_Float16)(e[4 + k] * inv); }
  *(half4*)(p + base0) = h0;
  *(half4*)(p + base1) = h1;
}

extern "C" void kernel_launch(void* const* d_in, const int* in_sizes, int n_in,
                              void* d_out, int out_size, void* d_ws, size_t ws_size,
                              hipStream_t stream) {
  (void)in_sizes; (void)n_in; (void)out_size;
  if ((long)ws_size < WS_NEED) return;  // workspace too small: leave out poisoned as a clear signal

  const float* inp  = (const float*)d_in[0];
  const float* ctx  = (const float*)d_in[1];
  const unsigned* msk = (const unsigned*)d_in[2];
  const float* W    = (const float*)d_in[3];
  const float* bias = (const float*)d_in[4];
  float* out = (float*)d_out;
  char* ws = (char*)d_ws;

  float*    Sb   = (float*)(ws + OFF_S);
  _Float16* Pb   = (_Float16*)(ws + OFF_P);
  _Float16* Wf   = (_Float16*)(ws + OFF_W);
  _Float16* QK   = (_Float16*)(ws + OFF_QK);
  _Float16* KT   = (_Float16*)(ws + OFF_KT);
  unsigned char* Mc = (unsigned char*)(ws + OFF_MASK);

  // 1. canonical mask + W fp16
  mask_canon<<<1, 256, 0, stream>>>(msk, Mc);
  cvt_f32_f16<<<1024, 256, 0, stream>>>(W, Wf, 1048576L);
  // 2. projection (cvt fused): QK = relu([inp;ctx] @ W^T + b), M=65536, N=1024, K=1024
  gemm_nt8<true, true><<<dim3(4, 256, 1), 512, 0, stream>>>(
      nullptr, inp, ctx, 0L, Wf, 0L, (void*)QK, 0L, bias, 1024, 1024);
  // 3. K^T per batch
  transpose_k<<<dim3(32, 16, 16), 256, 0, stream>>>(QK + 32768L * 1024, KT);
  // 4. two groups of 8 batches: (scores -> softmax) per 4-batch quad, then one PV for 8
  for (int g = 0; g < 2; g++) {
    for (int q = 0; q < 2; q++) {
      const int bp = g * 2 + q;
      const _Float16* Aq = QK + (long)bp * 4 * 2048 * 1024;
      const _Float16* Bk = QK + (32768L + (long)bp * 4 * 2048) * 1024;
      gemm_nt8<false, false><<<dim3(8, 8, 4), 512, 0, stream>>>(
          Aq, nullptr, nullptr, 2048L * 1024, Bk, 2048L * 1024,
          (void*)Sb, 2048L * 2048, nullptr, 1024, 2048);
      softmax_k<<<dim3(2048, 4), 256, 0, stream>>>(Sb, Pb + (long)q * 4 * 2048 * 2048, Mc, bp * 4);
    }
    gemm_nt8<false, false><<<dim3(4, 8, 8), 512, 0, stream>>>(
        Pb, nullptr, nullptr, 2048L * 2048, KT + (long)g * 8 * 1024 * 2048, 1024L * 2048,
        (void*)(out + (long)g * 8 * 2048 * 1024), 2048L * 1024, nullptr, 2048, 1024);
  }
}

// Round 3
// 852.447 us; speedup vs baseline: 1.1874x; 1.0271x over previous
//
#include <hip/hip_runtime.h>

typedef _Float16 half8 __attribute__((ext_vector_type(8)));
typedef _Float16 half4 __attribute__((ext_vector_type(4)));
typedef float floatx4 __attribute__((ext_vector_type(4)));

// ---------------- workspace layout (bytes) ----------------
// X fp16 region [0, 134217728) is dead after the projection GEMM; S/P alias it.
#define OFF_X    0L
#define OFF_S    0L                      // 4 batches * 2048*2048 fp32 = 67108864
#define OFF_P    67108864L               // 8 batches * 2048*2048 fp16 = 67108864
#define OFF_W    134217728L              // 1024*1024 fp16 = 2097152
#define OFF_QK   136314880L              // 65536*1024 fp16 (Q rows 0.., K rows 32768..)
#define OFF_KT   270532608L              // 16*1024*2048 fp16 = 67108864
#define OFF_MASK 337641472L              // 32768 u8
#define WS_NEED  337674240L

__device__ __forceinline__ void glds16(const void* g, void* l) {
  __builtin_amdgcn_global_load_lds(
      (__attribute__((address_space(1))) void*)(void*)(g),
      (__attribute__((address_space(3))) void*)(l), 16, 0, 0);
}

// ---------------- mask canonicalization ----------------
__global__ void mask_canon(const unsigned* __restrict__ raw,
                           unsigned char* __restrict__ outm) {
  __shared__ int flag;
  int t = threadIdx.x;
  if (t == 0) flag = 0;
  __syncthreads();
  int loc = 0;
  for (int i = t; i < 8192; i += 256)
    if (raw[i] > 1u) loc = 1;
  if (loc) flag = 1;
  __syncthreads();
  if (flag) {
    const unsigned char* b8 = (const unsigned char*)raw;
    for (int j = t; j < 32768; j += 256) outm[j] = (b8[j] != 0);
  } else {
    const int* r32 = (const int*)raw;
    for (int j = t; j < 32768; j += 256) outm[j] = (r32[j] != 0);
  }
}

// ---------------- fp32 -> fp16 convert ----------------
__global__ __launch_bounds__(256) void cvt_f32_f16(const float* __restrict__ x,
                                                   _Float16* __restrict__ y, long n) {
  long i = ((long)blockIdx.x * 256 + threadIdx.x) * 4;
  if (i + 3 < n) {
    float4 v = *(const float4*)(x + i);
    half4 h;
    h[0] = (_Float16)v.x; h[1] = (_Float16)v.y;
    h[2] = (_Float16)v.z; h[3] = (_Float16)v.w;
    *(half4*)(y + i) = h;
  }
}

// ---------------- NT GEMM, 256x256, 8 waves, A2/B3-buffer deep pipeline ----------------
// C[m,n] = sum_k A[m,k]*B[n,k]; A/B row stride == K.
// 512 threads = 8 waves (2M x 4N), per-wave 128x64, BK=64, 16x16x32 f16 MFMA.
// LDS 160 KiB exactly: A 2 x 32KB double-buffer, B 3 x 32KB triple-buffer.
// Per K-tile t: 4 phases, each = [ds_reads; 2x glds16; s_barrier; lgkmcnt(0);
// setprio(1); 16 MFMA; setprio(0); s_barrier].  Stages: ph0/ph1 -> A(t+1),
// ph2/ph3 -> B(t+2).  Single s_waitcnt vmcnt(4) at ph3-end (before barrier2):
// outstanding queue there = [B(t+1)x4][A(t+1)x4][B(t+2)x4]; keep newest 4 =
// B(t+2), drains A(t+1)+B(t+1) (both read starting next tile).  Issue-to-drain
// distance >= 3 phases (~1000+ cy >= HBM latency); never drains to 0 in loop.
// Region safety: every glds issue point is barrier-ordered after the last read
// of its destination buffer (A(t+1)->buf t^1 read last in tile t-1; B(t+2)->
// bq+2 mod 3, read last in tile t-1).  Chunk-XOR swizzle (row&7) on 128B rows:
// aliased read rows are 1024B apart -> 2-way max -> conflict-free (r1: 0).
template <bool EPI>
__global__ __launch_bounds__(512, 2)
void gemm_nt3(const _Float16* __restrict__ A, long sAz,
              const _Float16* __restrict__ B, long sBz,
              void* __restrict__ Cv, long sCz,
              const float* __restrict__ bias, int K, int ldc) {
  __shared__ _Float16 lds[81920];        // 163840 B
  const int t = threadIdx.x;
  const int l = t & 63;
  const int w = t >> 6;
  const int wr = w >> 2, wc = w & 3;
  const int l15 = l & 15, quad = l >> 4;
  const int srow = l >> 3;
  const int gchunk = (l & 7) ^ (srow & 7);
  const int sbase = w * 8;

  const _Float16* Ag = A + (long)blockIdx.z * sAz + (long)blockIdx.y * 256 * (long)K;
  const _Float16* Bg = B + (long)blockIdx.z * sBz + (long)blockIdx.x * 256 * (long)K;

  _Float16* const As = lds;              // 2 x 16384 halves
  _Float16* const Bs = lds + 32768;      // 3 x 16384 halves

  const int arow = wr * 128 + l15;
  const int brow = wc * 64 + l15;
  const int ccA = (quad ^ (arow & 7)) << 3;
  const int ccB = (quad ^ (brow & 7)) << 3;

  floatx4 acc[8][4] = {};
  const int NT = K >> 6;

#define STG(gp, dst, rnd, kt)                                                  \
  glds16(gp + (long)((rnd) * 64 + sbase + srow) * K + (kt) + gchunk * 8,       \
         (dst) + ((rnd) * 64 + sbase) * 64)
#define MM(mh)                                                                 \
  do {                                                                         \
    _Pragma("unroll") for (int mi_ = 0; mi_ < 4; ++mi_)                        \
      _Pragma("unroll") for (int ni_ = 0; ni_ < 4; ++ni_)                      \
        acc[(mh) * 4 + mi_][ni_] = __builtin_amdgcn_mfma_f32_16x16x32_f16(     \
            af[mi_], bf[ni_], acc[(mh) * 4 + mi_][ni_], 0, 0, 0);              \
  } while (0)
#define PH_HEAD()                                                              \
  __builtin_amdgcn_s_barrier();                                                \
  asm volatile("s_waitcnt lgkmcnt(0)" ::: "memory");                           \
  __builtin_amdgcn_s_setprio(1)
#define PH_TAIL()                                                              \
  __builtin_amdgcn_s_setprio(0)

  // prologue: A(0) x4, B(0) x4, B(1) x4; drain to newest 4 (=B(1))
  STG(Ag, As, 0, 0); STG(Ag, As, 1, 0); STG(Ag, As, 2, 0); STG(Ag, As, 3, 0);
  STG(Bg, Bs, 0, 0); STG(Bg, Bs, 1, 0); STG(Bg, Bs, 2, 0); STG(Bg, Bs, 3, 0);
  {
    const int k1 = (NT > 1 ? 64 : 0);
    _Float16* b1 = Bs + 16384;
    STG(Bg, b1, 0, k1); STG(Bg, b1, 1, k1); STG(Bg, b1, 2, k1); STG(Bg, b1, 3, k1);
  }
  asm volatile("s_waitcnt vmcnt(4)" ::: "memory");
  __builtin_amdgcn_s_barrier();

  int bq = 0, bq2 = 2;
  for (int tt = 0; tt < NT; ++tt) {
    const _Float16* Ap = As + (tt & 1) * 16384;
    const _Float16* Bp = Bs + bq * 16384;
    _Float16* Anx = As + ((tt + 1) & 1) * 16384;
    _Float16* Bnx = Bs + bq2 * 16384;
    const int kt1 = ((tt + 1 < NT) ? tt + 1 : NT - 1) << 6;   // clamped junk: never read
    const int kt2 = ((tt + 2 < NT) ? tt + 2 : NT - 1) << 6;
    half8 af[4], bf[4];

    // ---- ph0: bf(k0) + af(mh0,k0); stage A(t+1) r0,r1 ----
#pragma unroll
    for (int ni = 0; ni < 4; ++ni) bf[ni] = *(const half8*)(Bp + (brow + ni * 16) * 64 + ccB);
#pragma unroll
    for (int mi = 0; mi < 4; ++mi) af[mi] = *(const half8*)(Ap + (arow + mi * 16) * 64 + ccA);
    STG(Ag, Anx, 0, kt1);
    STG(Ag, Anx, 1, kt1);
    PH_HEAD();
    MM(0);
    PH_TAIL();
    __builtin_amdgcn_s_barrier();

    // ---- ph1: af(mh1,k0); stage A(t+1) r2,r3 ----
#pragma unroll
    for (int mi = 0; mi < 4; ++mi)
      af[mi] = *(const half8*)(Ap + (arow + (mi + 4) * 16) * 64 + ccA);
    STG(Ag, Anx, 2, kt1);
    STG(Ag, Anx, 3, kt1);
    PH_HEAD();
    MM(1);
    PH_TAIL();
    __builtin_amdgcn_s_barrier();

    // ---- ph2: bf(k1) + af(mh0,k1); stage B(t+2) r0,r1 ----
#pragma unroll
    for (int ni = 0; ni < 4; ++ni)
      bf[ni] = *(const half8*)(Bp + (brow + ni * 16) * 64 + (ccB ^ 32));
#pragma unroll
    for (int mi = 0; mi < 4; ++mi)
      af[mi] = *(const half8*)(Ap + (arow + mi * 16) * 64 + (ccA ^ 32));
    STG(Bg, Bnx, 0, kt2);
    STG(Bg, Bnx, 1, kt2);
    PH_HEAD();
    MM(0);
    PH_TAIL();
    __builtin_amdgcn_s_barrier();

    // ---- ph3: af(mh1,k1); stage B(t+2) r2,r3; vmcnt(4) ----
#pragma unroll
    for (int mi = 0; mi < 4; ++mi)
      af[mi] = *(const half8*)(Ap + (arow + (mi + 4) * 16) * 64 + (ccA ^ 32));
    STG(Bg, Bnx, 2, kt2);
    STG(Bg, Bnx, 3, kt2);
    PH_HEAD();
    MM(1);
    PH_TAIL();
    asm volatile("s_waitcnt vmcnt(4)" ::: "memory");
    __builtin_amdgcn_s_barrier();

    bq = (bq == 2) ? 0 : bq + 1;
    bq2 = (bq2 == 2) ? 0 : bq2 + 1;
  }
  asm volatile("s_waitcnt vmcnt(0)" ::: "memory");  // tail junk glds before LDS reuse
  __syncthreads();
#undef STG
#undef MM
#undef PH_HEAD
#undef PH_TAIL

  // ---------------- epilogue ----------------
  const long cbase = (long)blockIdx.z * sCz + (long)blockIdx.y * 256 * (long)ldc +
                     (long)blockIdx.x * 256;
  const int rowb = quad * 4;
  if constexpr (EPI) {
    // relu+bias, bounce through swizzled LDS tile (stride 264, chunk^row&7), then
    // fully-coalesced half8 stores.
    float bv[4];
#pragma unroll
    for (int ni = 0; ni < 4; ++ni) bv[ni] = bias[blockIdx.x * 256 + wc * 64 + ni * 16 + l15];
#pragma unroll
    for (int mi = 0; mi < 8; ++mi)
#pragma unroll
      for (int ni = 0; ni < 4; ++ni) {
        const int col = wc * 64 + ni * 16 + l15;
#pragma unroll
        for (int p = 0; p < 4; ++p) {
          const int row = wr * 128 + mi * 16 + rowb + p;
          lds[row * 264 + (((col >> 3) ^ (row & 7)) << 3) + (col & 7)] =
              (_Float16)fmaxf(acc[mi][ni][p] + bv[ni], 0.f);
        }
      }
    __syncthreads();
    _Float16* Cp = (_Float16*)Cv + cbase;
#pragma unroll
    for (int pp = 0; pp < 16; ++pp) {
      const int r = (t >> 5) + 16 * pp;
      const int c = t & 31;
      half8 v = *(const half8*)(lds + r * 264 + ((c ^ (r & 7)) << 3));
      *(half8*)(Cp + (long)r * ldc + c * 8) = v;
    }
  } else {
    float* Cp = (float*)Cv + cbase;
#pragma unroll
    for (int mi = 0; mi < 8; ++mi)
#pragma unroll
      for (int ni = 0; ni < 4; ++ni) {
        const int col = wc * 64 + ni * 16 + l15;
#pragma unroll
        for (int p = 0; p < 4; ++p) {
          const int row = wr * 128 + mi * 16 + rowb + p;
          Cp[(long)row * ldc + col] = acc[mi][ni][p];
        }
      }
  }
}

// ---------------- K transpose (per batch, fp16) ----------------
__global__ __launch_bounds__(256) void transpose_k(const _Float16* __restrict__ Km,
                                                   _Float16* __restrict__ KT) {
  __shared__ _Float16 tile[64 * 72];
  const int t = threadIdx.x;
  const long b = blockIdx.z;
  const _Float16* src = Km + (b * 2048 + blockIdx.x * 64) * 1024 + blockIdx.y * 64;
  {
    const int jl = t >> 2, hc = (t & 3) * 16;
    half8 v0 = *(const half8*)(src + (long)jl * 1024 + hc);
    half8 v1 = *(const half8*)(src + (long)jl * 1024 + hc + 8);
    *(half8*)&tile[jl * 72 + hc] = v0;
    *(half8*)&tile[jl * 72 + hc + 8] = v1;
  }
  __syncthreads();
  {
    const int hl = t >> 2, jc = (t & 3) * 16;
    half8 o0, o1;
#pragma unroll
    for (int jj = 0; jj < 8; jj++) o0[jj] = tile[(jc + jj) * 72 + hl];
#pragma unroll
    for (int jj = 0; jj < 8; jj++) o1[jj] = tile[(jc + 8 + jj) * 72 + hl];
    long off = (b * 1024 + blockIdx.y * 64 + hl) * 2048 + blockIdx.x * 64 + jc;
    *(half8*)(KT + off) = o0;
    *(half8*)(KT + off + 8) = o1;
  }
}

// ---------------- masked softmax: S fp32 row -> P fp16 row ----------------
__global__ __launch_bounds__(256) void softmax_k(const float* __restrict__ S,
                                                 _Float16* __restrict__ P,
                                                 const unsigned char* __restrict__ mask,
                                                 int b0) {
  const int i = blockIdx.x, z = blockIdx.y, t = threadIdx.x;
  const float* s = S + ((long)z * 2048 + i) * 2048;
  const unsigned char* mrow = mask + (long)(b0 + z) * 2048;
  const int base0 = t * 4, base1 = 1024 + t * 4;
  float4 a0 = *(const float4*)(s + base0);
  float4 a1 = *(const float4*)(s + base1);
  float v[8] = {a0.x, a0.y, a0.z, a0.w, a1.x, a1.y, a1.z, a1.w};
  const float NINF = -__builtin_inff();
#pragma unroll
  for (int k = 0; k < 4; k++) {
    if (mrow[base0 + k]) v[k] = NINF;
    if (mrow[base1 + k]) v[4 + k] = NINF;
  }
  float mx = v[0];
#pragma unroll
  for (int k = 1; k < 8; k++) mx = fmaxf(mx, v[k]);
#pragma unroll
  for (int o = 32; o >= 1; o >>= 1) mx = fmaxf(mx, __shfl_xor(mx, o, 64));
  __shared__ float redm[4], reds[4];
  if ((t & 63) == 0) redm[t >> 6] = mx;
  __syncthreads();
  mx = fmaxf(fmaxf(redm[0], redm[1]), fmaxf(redm[2], redm[3]));
  float e[8], sm = 0.f;
#pragma unroll
  for (int k = 0; k < 8; k++) { e[k] = __expf(v[k] - mx); sm += e[k]; }
#pragma unroll
  for (int o = 32; o >= 1; o >>= 1) sm += __shfl_xor(sm, o, 64);
  if ((t & 63) == 0) reds[t >> 6] = sm;
  __syncthreads();
  sm = reds[0] + reds[1] + reds[2] + reds[3];
  const float inv = 1.0f / sm;   // never a fully-masked row
  _Float16* p = P + ((long)z * 2048 + i) * 2048;
  half4 h0, h1;
#pragma unroll
  for (int k = 0; k < 4; k++) { h0[k] = (_Float16)(e[k] * inv); h1[k] = (_Float16)(e[4 + k] * inv); }
  *(half4*)(p + base0) = h0;
  *(half4*)(p + base1) = h1;
}

extern "C" void kernel_launch(void* const* d_in, const int* in_sizes, int n_in,
                              void* d_out, int out_size, void* d_ws, size_t ws_size,
                              hipStream_t stream) {
  (void)in_sizes; (void)n_in; (void)out_size;
  if ((long)ws_size < WS_NEED) return;  // workspace too small: leave out poisoned as a clear signal

  const float* inp  = (const float*)d_in[0];
  const float* ctx  = (const float*)d_in[1];
  const unsigned* msk = (const unsigned*)d_in[2];
  const float* W    = (const float*)d_in[3];
  const float* bias = (const float*)d_in[4];
  float* out = (float*)d_out;
  char* ws = (char*)d_ws;

  _Float16* Xf   = (_Float16*)(ws + OFF_X);
  float*    Sb   = (float*)(ws + OFF_S);
  _Float16* Pb   = (_Float16*)(ws + OFF_P);
  _Float16* Wf   = (_Float16*)(ws + OFF_W);
  _Float16* QK   = (_Float16*)(ws + OFF_QK);
  _Float16* KT   = (_Float16*)(ws + OFF_KT);
  unsigned char* Mc = (unsigned char*)(ws + OFF_MASK);

  // 1. canonical mask + fp16 conversions
  mask_canon<<<1, 256, 0, stream>>>(msk, Mc);
  cvt_f32_f16<<<32768, 256, 0, stream>>>(inp, Xf, 33554432L);
  cvt_f32_f16<<<32768, 256, 0, stream>>>(ctx, Xf + 33554432L, 33554432L);
  cvt_f32_f16<<<1024, 256, 0, stream>>>(W, Wf, 1048576L);
  // 2. projection: QK = relu([inp;ctx] @ W^T + b), M=65536, N=1024, K=1024
  gemm_nt3<true><<<dim3(4, 256, 1), 512, 0, stream>>>(Xf, 0L, Wf, 0L, (void*)QK, 0L,
                                                      bias, 1024, 1024);
  // 3. K^T per batch
  transpose_k<<<dim3(32, 16, 16), 256, 0, stream>>>(QK + 32768L * 1024, KT);
  // 4. two groups of 8 batches: (scores -> softmax) per 4-batch quad, then one PV for 8
  for (int g = 0; g < 2; g++) {
    for (int q = 0; q < 2; q++) {
      const int bp = g * 2 + q;
      const _Float16* Aq = QK + (long)bp * 4 * 2048 * 1024;
      const _Float16* Bk = QK + (32768L + (long)bp * 4 * 2048) * 1024;
      gemm_nt3<false><<<dim3(8, 8, 4), 512, 0, stream>>>(
          Aq, 2048L * 1024, Bk, 2048L * 1024, (void*)Sb, 2048L * 2048, nullptr, 1024, 2048);
      softmax_k<<<dim3(2048, 4), 256, 0, stream>>>(Sb, Pb + (long)q * 4 * 2048 * 2048, Mc, bp * 4);
    }
    gemm_nt3<false><<<dim3(4, 8, 8), 512, 0, stream>>>(
        Pb, 2048L * 2048, KT + (long)g * 8 * 1024 * 2048, 1024L * 2048,
        (void*)(out + (long)g * 8 * 2048 * 1024), 2048L * 1024, nullptr, 2048, 1024);
  }
}

// Round 4
// 836.080 us; speedup vs baseline: 1.2107x; 1.0196x over previous
//
#include <hip/hip_runtime.h>

typedef _Float16 half8 __attribute__((ext_vector_type(8)));
typedef _Float16 half4 __attribute__((ext_vector_type(4)));
typedef float floatx4 __attribute__((ext_vector_type(4)));

// ---------------- workspace layout (bytes) ----------------
// X fp16 region [0, 134217728) is dead after the projection GEMM; S/P alias it.
#define OFF_X    0L
#define OFF_S    0L                      // 4 batches * 2048*2048 fp32 = 67108864
#define OFF_P    67108864L               // 8 batches * 2048*2048 fp16 = 67108864
#define OFF_W    134217728L              // 1024*1024 fp16 = 2097152
#define OFF_QK   136314880L              // 65536*1024 fp16 (Q rows 0.., K rows 32768..)
#define OFF_KT   270532608L              // 16*1024*2048 fp16 = 67108864
#define OFF_MASK 337641472L              // 32768 u8
#define WS_NEED  337674240L

__device__ __forceinline__ void glds16(const void* g, void* l) {
  __builtin_amdgcn_global_load_lds(
      (__attribute__((address_space(1))) void*)(void*)(g),
      (__attribute__((address_space(3))) void*)(l), 16, 0, 0);
}

// ---------------- mask canonicalization ----------------
__global__ void mask_canon(const unsigned* __restrict__ raw,
                           unsigned char* __restrict__ outm) {
  __shared__ int flag;
  int t = threadIdx.x;
  if (t == 0) flag = 0;
  __syncthreads();
  int loc = 0;
  for (int i = t; i < 8192; i += 256)
    if (raw[i] > 1u) loc = 1;
  if (loc) flag = 1;
  __syncthreads();
  if (flag) {
    const unsigned char* b8 = (const unsigned char*)raw;
    for (int j = t; j < 32768; j += 256) outm[j] = (b8[j] != 0);
  } else {
    const int* r32 = (const int*)raw;
    for (int j = t; j < 32768; j += 256) outm[j] = (r32[j] != 0);
  }
}

// ---------------- fp32 -> fp16 convert ----------------
__global__ __launch_bounds__(256) void cvt_f32_f16(const float* __restrict__ x,
                                                   _Float16* __restrict__ y, long n) {
  long i = ((long)blockIdx.x * 256 + threadIdx.x) * 4;
  if (i + 3 < n) {
    float4 v = *(const float4*)(x + i);
    half4 h;
    h[0] = (_Float16)v.x; h[1] = (_Float16)v.y;
    h[2] = (_Float16)v.z; h[3] = (_Float16)v.w;
    *(half4*)(y + i) = h;
  }
}

// ---------------- NT GEMM, 256x256, 8 waves, read-ahead pipelined ----------------
// C[m,n] = sum_k A[m,k]*B[n,k]; A/B row stride == K.
// 512 threads = 8 waves (2M x 4N), per-wave 128x64, BK=64, 16x16x32 f16 MFMA.
// LDS 160 KiB: A 2x32KB double-buffer, B 3x32KB triple-buffer.
// READ-AHEAD SCHEDULE (T3+T4, counted lgkm AND vmcnt): fragment regs ping-pong
// (afP/afQ, bfE/bfO).  Each phase issues the NEXT phase's ds_reads, then waits
// lgkmcnt(#just-issued) -- guaranteeing the PREVIOUS phase's reads (DS retires
// in order) while its own stay in flight under the MFMA.  One barrier/phase.
//   ph0: rd afQ(mh1,k0)[4]; glds A(t+1)x4;        lgkm(4);  bar; MM(0,afP,bfE)
//   ph1: rd bfO,afP(k1)[8]; glds B(t+2)x2;        lgkm(8);  bar; MM(1,afQ,bfE)
//   ph2: rd afQ(mh1,k1)[4]; glds B(t+2)x2;        lgkm(4);  bar; MM(0,afP,bfO)
//   ph3: vmcnt(4); bar;  rd bfE,afP(t+1,k0)[8];   lgkm(8);       MM(1,afQ,bfO)
// ph3's vmcnt(4)+barrier publishes ALL waves' A(t+1)/B(t+1) glds before the
// next-tile read-ahead (vmcnt is per-wave; the barrier makes it global).
// Queue at ph3: [B(t+1)x4][A(t+1)x4][B(t+2)x4] -> keep newest 4 = B(t+2);
// youngest drained load is 3 phases old (~HBM latency).  Never drains to 0.
// sched_barrier(0) after each counted wait: hipcc hoists reg-only MFMA past
// inline-asm waitcnt otherwise (guide rule #18).
template <bool EPI>
__global__ __launch_bounds__(512, 2)
void gemm_nt5(const _Float16* __restrict__ A, long sAz,
              const _Float16* __restrict__ B, long sBz,
              void* __restrict__ Cv, long sCz,
              const float* __restrict__ bias, int K, int ldc) {
  __shared__ _Float16 lds[81920];        // 163840 B
  const int t = threadIdx.x;
  const int l = t & 63;
  const int w = t >> 6;
  const int wr = w >> 2, wc = w & 3;
  const int l15 = l & 15, quad = l >> 4;
  const int srow = l >> 3;
  const int gchunk = (l & 7) ^ (srow & 7);
  const int sbase = w * 8;

  // XCD-chunked block swizzle (bijective; all launches have nwg % 8 == 0):
  // consecutive work-ids (which share A-panels) land on one XCD's L2.
  unsigned bx, by, bz;
  {
    const unsigned gx = gridDim.x, gy = gridDim.y, gz = gridDim.z;
    const unsigned nwg = gx * gy * gz;
    unsigned lin = blockIdx.x + gx * (blockIdx.y + gy * blockIdx.z);
    if ((nwg & 7u) == 0u) lin = (lin & 7u) * (nwg >> 3) + (lin >> 3);
    bx = lin % gx;
    const unsigned rem = lin / gx;
    by = rem % gy;
    bz = rem / gy;
  }

  const _Float16* Ag = A + (long)bz * sAz + (long)by * 256 * (long)K;
  const _Float16* Bg = B + (long)bz * sBz + (long)bx * 256 * (long)K;

  _Float16* const As = lds;              // 2 x 16384 halves
  _Float16* const Bs = lds + 32768;      // 3 x 16384 halves

  const int arow = wr * 128 + l15;
  const int brow = wc * 64 + l15;
  const int ccA = (quad ^ (arow & 7)) << 3;
  const int ccB = (quad ^ (brow & 7)) << 3;

  floatx4 acc[8][4] = {};
  half8 afP[4], afQ[4], bfE[4], bfO[4];
  const int NT = K >> 6;

#define STG(gp, dst, rnd, kt)                                                  \
  glds16(gp + (long)((rnd) * 64 + sbase + srow) * K + (kt) + gchunk * 8,       \
         (dst) + ((rnd) * 64 + sbase) * 64)
#define RDA(DST, AP, mh, kx)                                                   \
  _Pragma("unroll") for (int mi_ = 0; mi_ < 4; ++mi_)                          \
      DST[mi_] = *(const half8*)((AP) + (arow + ((mh) * 4 + mi_) * 16) * 64 +  \
                                 (ccA ^ ((kx) * 32)));
#define RDB(DST, BP, kx)                                                       \
  _Pragma("unroll") for (int ni_ = 0; ni_ < 4; ++ni_)                          \
      DST[ni_] = *(const half8*)((BP) + (brow + ni_ * 16) * 64 +               \
                                 (ccB ^ ((kx) * 32)));
#define MM(mh, AF, BF)                                                         \
  do {                                                                         \
    __builtin_amdgcn_s_setprio(1);                                             \
    _Pragma("unroll") for (int mi_ = 0; mi_ < 4; ++mi_)                        \
      _Pragma("unroll") for (int ni_ = 0; ni_ < 4; ++ni_)                      \
        acc[(mh) * 4 + mi_][ni_] = __builtin_amdgcn_mfma_f32_16x16x32_f16(     \
            AF[mi_], BF[ni_], acc[(mh) * 4 + mi_][ni_], 0, 0, 0);              \
    __builtin_amdgcn_s_setprio(0);                                             \
  } while (0)
#define WAIT_LGKM(n)                                                           \
  asm volatile("s_waitcnt lgkmcnt(" #n ")" ::: "memory");                      \
  __builtin_amdgcn_sched_barrier(0)

  // prologue: A(0) x4, B(0) x4, B(1) x4; drain to newest 4 (=B(1))
  STG(Ag, As, 0, 0); STG(Ag, As, 1, 0); STG(Ag, As, 2, 0); STG(Ag, As, 3, 0);
  STG(Bg, Bs, 0, 0); STG(Bg, Bs, 1, 0); STG(Bg, Bs, 2, 0); STG(Bg, Bs, 3, 0);
  {
    const int k1 = (NT > 1 ? 64 : 0);
    _Float16* b1 = Bs + 16384;
    STG(Bg, b1, 0, k1); STG(Bg, b1, 1, k1); STG(Bg, b1, 2, k1); STG(Bg, b1, 3, k1);
  }
  asm volatile("s_waitcnt vmcnt(4)" ::: "memory");
  __builtin_amdgcn_s_barrier();
  // pre-loop read-ahead for tile 0 phase 0
  RDB(bfE, Bs, 0);
  RDA(afP, As, 0, 0);

  int bq = 0, bq2 = 2;
  for (int tt = 0; tt < NT; ++tt) {
    const _Float16* Ap_ = As + (tt & 1) * 16384;
    const _Float16* Bp_ = Bs + bq * 16384;
    _Float16* Anx = As + ((tt + 1) & 1) * 16384;
    _Float16* Bnx = Bs + bq2 * 16384;
    const int bqN = (bq == 2) ? 0 : bq + 1;
    const _Float16* BpN_ = Bs + bqN * 16384;
    const int kt1 = ((tt + 1 < NT) ? tt + 1 : NT - 1) << 6;   // clamped junk: never read
    const int kt2 = ((tt + 2 < NT) ? tt + 2 : NT - 1) << 6;

    // ---- ph0 ----
    RDA(afQ, Ap_, 1, 0);
    STG(Ag, Anx, 0, kt1); STG(Ag, Anx, 1, kt1);
    STG(Ag, Anx, 2, kt1); STG(Ag, Anx, 3, kt1);
    WAIT_LGKM(4);
    __builtin_amdgcn_s_barrier();
    MM(0, afP, bfE);

    // ---- ph1 ----
    RDB(bfO, Bp_, 1);
    RDA(afP, Ap_, 0, 1);
    STG(Bg, Bnx, 0, kt2); STG(Bg, Bnx, 1, kt2);
    WAIT_LGKM(8);
    __builtin_amdgcn_s_barrier();
    MM(1, afQ, bfE);

    // ---- ph2 ----
    RDA(afQ, Ap_, 1, 1);
    STG(Bg, Bnx, 2, kt2); STG(Bg, Bnx, 3, kt2);
    WAIT_LGKM(4);
    __builtin_amdgcn_s_barrier();
    MM(0, afP, bfO);

    // ---- ph3: publish A(t+1)/B(t+1), read-ahead tile t+1 ----
    asm volatile("s_waitcnt vmcnt(4)" ::: "memory");
    __builtin_amdgcn_s_barrier();
    RDB(bfE, BpN_, 0);
    RDA(afP, Anx, 0, 0);
    WAIT_LGKM(8);
    MM(1, afQ, bfO);

    bq = bqN;
    bq2 = (bq2 == 2) ? 0 : bq2 + 1;
  }
  asm volatile("s_waitcnt vmcnt(0)" ::: "memory");  // tail junk glds before LDS reuse
  __syncthreads();
#undef STG
#undef RDA
#undef RDB
#undef MM
#undef WAIT_LGKM

  // ---------------- epilogue ----------------
  const long cbase = (long)bz * sCz + (long)by * 256 * (long)ldc + (long)bx * 256;
  const int rowb = quad * 4;
  if constexpr (EPI) {
    // relu+bias, bounce through swizzled LDS tile (stride 268: 4-row spacing is
    // 24 banks -> quad rows hit distinct banks; chunk^row&7 swizzle), then
    // fully-coalesced half8 stores.
    float bv[4];
#pragma unroll
    for (int ni = 0; ni < 4; ++ni) bv[ni] = bias[bx * 256 + wc * 64 + ni * 16 + l15];
#pragma unroll
    for (int mi = 0; mi < 8; ++mi)
#pragma unroll
      for (int ni = 0; ni < 4; ++ni) {
        const int col = wc * 64 + ni * 16 + l15;
#pragma unroll
        for (int p = 0; p < 4; ++p) {
          const int row = wr * 128 + mi * 16 + rowb + p;
          lds[row * 268 + (((col >> 3) ^ (row & 7)) << 3) + (col & 7)] =
              (_Float16)fmaxf(acc[mi][ni][p] + bv[ni], 0.f);
        }
      }
    __syncthreads();
    _Float16* Cp = (_Float16*)Cv + cbase;
#pragma unroll
    for (int pp = 0; pp < 16; ++pp) {
      const int r = (t >> 5) + 16 * pp;
      const int c = t & 31;
      half8 v = *(const half8*)(lds + r * 268 + ((c ^ (r & 7)) << 3));
      *(half8*)(Cp + (long)r * ldc + c * 8) = v;
    }
  } else {
    float* Cp = (float*)Cv + cbase;
#pragma unroll
    for (int mi = 0; mi < 8; ++mi)
#pragma unroll
      for (int ni = 0; ni < 4; ++ni) {
        const int col = wc * 64 + ni * 16 + l15;
#pragma unroll
        for (int p = 0; p < 4; ++p) {
          const int row = wr * 128 + mi * 16 + rowb + p;
          Cp[(long)row * ldc + col] = acc[mi][ni][p];
        }
      }
  }
}

// ---------------- K transpose (per batch, fp16) ----------------
__global__ __launch_bounds__(256) void transpose_k(const _Float16* __restrict__ Km,
                                                   _Float16* __restrict__ KT) {
  __shared__ _Float16 tile[64 * 72];
  const int t = threadIdx.x;
  const long b = blockIdx.z;
  const _Float16* src = Km + (b * 2048 + blockIdx.x * 64) * 1024 + blockIdx.y * 64;
  {
    const int jl = t >> 2, hc = (t & 3) * 16;
    half8 v0 = *(const half8*)(src + (long)jl * 1024 + hc);
    half8 v1 = *(const half8*)(src + (long)jl * 1024 + hc + 8);
    *(half8*)&tile[jl * 72 + hc] = v0;
    *(half8*)&tile[jl * 72 + hc + 8] = v1;
  }
  __syncthreads();
  {
    const int hl = t >> 2, jc = (t & 3) * 16;
    half8 o0, o1;
#pragma unroll
    for (int jj = 0; jj < 8; jj++) o0[jj] = tile[(jc + jj) * 72 + hl];
#pragma unroll
    for (int jj = 0; jj < 8; jj++) o1[jj] = tile[(jc + 8 + jj) * 72 + hl];
    long off = (b * 1024 + blockIdx.y * 64 + hl) * 2048 + blockIdx.x * 64 + jc;
    *(half8*)(KT + off) = o0;
    *(half8*)(KT + off + 8) = o1;
  }
}

// ---------------- masked softmax: S fp32 row -> P fp16 row ----------------
__global__ __launch_bounds__(256) void softmax_k(const float* __restrict__ S,
                                                 _Float16* __restrict__ P,
                                                 const unsigned char* __restrict__ mask,
                                                 int b0) {
  const int i = blockIdx.x, z = blockIdx.y, t = threadIdx.x;
  const float* s = S + ((long)z * 2048 + i) * 2048;
  const unsigned char* mrow = mask + (long)(b0 + z) * 2048;
  const int base0 = t * 4, base1 = 1024 + t * 4;
  float4 a0 = *(const float4*)(s + base0);
  float4 a1 = *(const float4*)(s + base1);
  float v[8] = {a0.x, a0.y, a0.z, a0.w, a1.x, a1.y, a1.z, a1.w};
  const float NINF = -__builtin_inff();
#pragma unroll
  for (int k = 0; k < 4; k++) {
    if (mrow[base0 + k]) v[k] = NINF;
    if (mrow[base1 + k]) v[4 + k] = NINF;
  }
  float mx = v[0];
#pragma unroll
  for (int k = 1; k < 8; k++) mx = fmaxf(mx, v[k]);
#pragma unroll
  for (int o = 32; o >= 1; o >>= 1) mx = fmaxf(mx, __shfl_xor(mx, o, 64));
  __shared__ float redm[4], reds[4];
  if ((t & 63) == 0) redm[t >> 6] = mx;
  __syncthreads();
  mx = fmaxf(fmaxf(redm[0], redm[1]), fmaxf(redm[2], redm[3]));
  float e[8], sm = 0.f;
#pragma unroll
  for (int k = 0; k < 8; k++) { e[k] = __expf(v[k] - mx); sm += e[k]; }
#pragma unroll
  for (int o = 32; o >= 1; o >>= 1) sm += __shfl_xor(sm, o, 64);
  if ((t & 63) == 0) reds[t >> 6] = sm;
  __syncthreads();
  sm = reds[0] + reds[1] + reds[2] + reds[3];
  const float inv = 1.0f / sm;   // never a fully-masked row
  _Float16* p = P + ((long)z * 2048 + i) * 2048;
  half4 h0, h1;
#pragma unroll
  for (int k = 0; k < 4; k++) { h0[k] = (_Float16)(e[k] * inv); h1[k] = (_Float16)(e[4 + k] * inv); }
  *(half4*)(p + base0) = h0;
  *(half4*)(p + base1) = h1;
}

extern "C" void kernel_launch(void* const* d_in, const int* in_sizes, int n_in,
                              void* d_out, int out_size, void* d_ws, size_t ws_size,
                              hipStream_t stream) {
  (void)in_sizes; (void)n_in; (void)out_size;
  if ((long)ws_size < WS_NEED) return;  // workspace too small: leave out poisoned as a clear signal

  const float* inp  = (const float*)d_in[0];
  const float* ctx  = (const float*)d_in[1];
  const unsigned* msk = (const unsigned*)d_in[2];
  const float* W    = (const float*)d_in[3];
  const float* bias = (const float*)d_in[4];
  float* out = (float*)d_out;
  char* ws = (char*)d_ws;

  _Float16* Xf   = (_Float16*)(ws + OFF_X);
  float*    Sb   = (float*)(ws + OFF_S);
  _Float16* Pb   = (_Float16*)(ws + OFF_P);
  _Float16* Wf   = (_Float16*)(ws + OFF_W);
  _Float16* QK   = (_Float16*)(ws + OFF_QK);
  _Float16* KT   = (_Float16*)(ws + OFF_KT);
  unsigned char* Mc = (unsigned char*)(ws + OFF_MASK);

  // 1. canonical mask + fp16 conversions
  mask_canon<<<1, 256, 0, stream>>>(msk, Mc);
  cvt_f32_f16<<<32768, 256, 0, stream>>>(inp, Xf, 33554432L);
  cvt_f32_f16<<<32768, 256, 0, stream>>>(ctx, Xf + 33554432L, 33554432L);
  cvt_f32_f16<<<1024, 256, 0, stream>>>(W, Wf, 1048576L);
  // 2. projection: QK = relu([inp;ctx] @ W^T + b), M=65536, N=1024, K=1024
  gemm_nt5<true><<<dim3(4, 256, 1), 512, 0, stream>>>(Xf, 0L, Wf, 0L, (void*)QK, 0L,
                                                      bias, 1024, 1024);
  // 3. K^T per batch
  transpose_k<<<dim3(32, 16, 16), 256, 0, stream>>>(QK + 32768L * 1024, KT);
  // 4. two groups of 8 batches: (scores -> softmax) per 4-batch quad, then one PV for 8
  for (int g = 0; g < 2; g++) {
    for (int q = 0; q < 2; q++) {
      const int bp = g * 2 + q;
      const _Float16* Aq = QK + (long)bp * 4 * 2048 * 1024;
      const _Float16* Bk = QK + (32768L + (long)bp * 4 * 2048) * 1024;
      gemm_nt5<false><<<dim3(8, 8, 4), 512, 0, stream>>>(
          Aq, 2048L * 1024, Bk, 2048L * 1024, (void*)Sb, 2048L * 2048, nullptr, 1024, 2048);
      softmax_k<<<dim3(2048, 4), 256, 0, stream>>>(Sb, Pb + (long)q * 4 * 2048 * 2048, Mc, bp * 4);
    }
    gemm_nt5<false><<<dim3(4, 8, 8), 512, 0, stream>>>(
        Pb, 2048L * 2048, KT + (long)g * 8 * 1024 * 2048, 1024L * 2048,
        (void*)(out + (long)g * 8 * 2048 * 1024), 2048L * 1024, nullptr, 2048, 1024);
  }
}